// Round 2
// baseline (1395.328 us; speedup 1.0000x reference)
//
#include <hip/hip_runtime.h>

#define IN_DIM 8
#define HID 32
#define OUT_DIM 32

// ws layout (4-byte units):
//  [0..7]   per-channel sum      (zeroed each call)
//  [8..15]  per-channel sumsq    (zeroed each call)
//  [16..23] mean
//  [24..31] rstd
//  [32]     int64-mode flag (int)
// agg lives in d_out (prep fully initializes it; mlp runs in-place).

__global__ void init_kernel(float* ws, const int* __restrict__ ei_raw, int two_e) {
  __shared__ int s_nonzero;
  if (threadIdx.x == 0) s_nonzero = 0;
  __syncthreads();
  if (threadIdx.x < 16) ws[threadIdx.x] = 0.f;
  // If edge_index is stored as int64 (lo/hi 32-bit pairs, little-endian), all
  // hi words are 0 (indices < 50000). If int32, odd words are real indices —
  // among 2048 uniform samples in [0,50000) the all-zero probability is nil.
  int nz = 0;
  for (int i = threadIdx.x; i < 2048 && (2 * i + 1) < 2 * two_e; i += blockDim.x) {
    if (ei_raw[2 * i + 1] != 0) nz = 1;
  }
  if (nz) atomicOr(&s_nonzero, 1);
  __syncthreads();
  if (threadIdx.x == 0) ((int*)ws)[32] = (s_nonzero == 0) ? 1 : 0;
}

__global__ void stats_kernel(const float* __restrict__ x, int n, float* ws) {
  __shared__ float ssum[8], ssq[8];
  if (threadIdx.x < 8) { ssum[threadIdx.x] = 0.f; ssq[threadIdx.x] = 0.f; }
  __syncthreads();
  int total = n * IN_DIM;
  int c = threadIdx.x & 7;  // grid*block divisible by 8 -> channel fixed per thread
  float s = 0.f, s2 = 0.f;
  for (int i = blockIdx.x * blockDim.x + threadIdx.x; i < total;
       i += gridDim.x * blockDim.x) {
    float v = x[i];
    s += v; s2 += v * v;
  }
  atomicAdd(&ssum[c], s);
  atomicAdd(&ssq[c], s2);
  __syncthreads();
  if (threadIdx.x < 8) {
    atomicAdd(&ws[threadIdx.x], ssum[threadIdx.x]);
    atomicAdd(&ws[8 + threadIdx.x], ssq[threadIdx.x]);
  }
}

__global__ void finalize_stats(float* ws, float inv_n) {
  int t = threadIdx.x;
  if (t < 8) {
    float mean = ws[t] * inv_n;
    float var = ws[8 + t] * inv_n - mean * mean;
    ws[16 + t] = mean;
    ws[24 + t] = rsqrtf(var + 1e-5f);
  }
}

// agg[node][o] = nc_bias[o] + sum_i xn[node][i] * W_root[i][o]
__global__ __launch_bounds__(256) void prep_kernel(
    const float* __restrict__ x, const float* __restrict__ Wroot,
    const float* __restrict__ ncb, const float* __restrict__ ws,
    float* __restrict__ agg, int n) {
  int gid = blockIdx.x * blockDim.x + threadIdx.x;
  int node = gid >> 5, o = gid & 31;
  if (node >= n) return;
  float xs[8];
#pragma unroll
  for (int i = 0; i < 8; ++i)
    xs[i] = (x[(size_t)node * 8 + i] - ws[16 + i]) * ws[24 + i];
  float acc = ncb[o];
#pragma unroll
  for (int i = 0; i < 8; ++i) acc += xs[i] * Wroot[i * 32 + o];
  agg[(size_t)node * 32 + o] = acc;
}

// Fused per-edge: MLP(edge_attr) -> relu -> w[8][32]; msg = xn[src].w; atomic scatter.
// 2 edges per thread: each broadcast LDS weight read feeds both accumulator chains.
__global__ __launch_bounds__(256) void edge_kernel(
    const float* __restrict__ ea, const float* __restrict__ x,
    const float* __restrict__ W1, const float* __restrict__ b1,
    const float* __restrict__ W2, const float* __restrict__ b2,
    const float* __restrict__ W3, const float* __restrict__ b3,
    const float* __restrict__ ws, const int* __restrict__ ei_raw,
    float* __restrict__ agg, int nE) {
  __shared__ float sW1[256];
  __shared__ float sW2[1024];
  __shared__ float sW3T[8192];  // sW3T[(i*32+o)*32 + k] = W3[k*256 + i*32 + o]
  __shared__ float sB1[32], sB2[32], sB3[256];

  for (int i = threadIdx.x; i < 256; i += 256) sW1[i] = W1[i];
  for (int i = threadIdx.x; i < 1024; i += 256) sW2[i] = W2[i];
  for (int i = threadIdx.x; i < 8192; i += 256) {
    int k = i >> 8, j = i & 255;  // coalesced global read of W3[k][j]
    sW3T[j * 32 + k] = W3[i];
  }
  if (threadIdx.x < 32) { sB1[threadIdx.x] = b1[threadIdx.x]; sB2[threadIdx.x] = b2[threadIdx.x]; }
  for (int i = threadIdx.x; i < 256; i += 256) sB3[i] = b3[i];
  __syncthreads();

  int mode64 = ((const int*)ws)[32];
  int t = blockIdx.x * blockDim.x + threadIdx.x;
  int e0 = 2 * t, e1 = 2 * t + 1;
  if (e0 >= nE) return;
  bool has1 = (e1 < nE);

  int src0 = mode64 ? ei_raw[2 * e0] : ei_raw[e0];
  int dst0 = mode64 ? ei_raw[2 * (nE + e0)] : ei_raw[nE + e0];
  int src1 = 0, dst1 = 0;
  if (has1) {
    src1 = mode64 ? ei_raw[2 * e1] : ei_raw[e1];
    dst1 = mode64 ? ei_raw[2 * (nE + e1)] : ei_raw[nE + e1];
  }

  float xsa[8], xsb[8];
#pragma unroll
  for (int i = 0; i < 8; ++i) {
    float m = ws[16 + i], r = ws[24 + i];
    xsa[i] = (x[(size_t)src0 * 8 + i] - m) * r;
    xsb[i] = has1 ? (x[(size_t)src1 * 8 + i] - m) * r : 0.f;
  }

  // ---- edge 0: h2a ----
  float h2a[32];
  {
    float a[8];
#pragma unroll
    for (int i = 0; i < 8; ++i) a[i] = ea[(size_t)e0 * 8 + i];
    float h1[32];
#pragma unroll
    for (int o = 0; o < 32; ++o) h1[o] = sB1[o];
#pragma unroll
    for (int i = 0; i < 8; ++i)
#pragma unroll
      for (int o = 0; o < 32; ++o) h1[o] += a[i] * sW1[i * 32 + o];
#pragma unroll
    for (int o = 0; o < 32; ++o) h1[o] = fmaxf(h1[o], 0.f);
#pragma unroll
    for (int o = 0; o < 32; ++o) h2a[o] = sB2[o];
#pragma unroll
    for (int k = 0; k < 32; ++k)
#pragma unroll
      for (int o = 0; o < 32; ++o) h2a[o] += h1[k] * sW2[k * 32 + o];
#pragma unroll
    for (int o = 0; o < 32; ++o) h2a[o] = fmaxf(h2a[o], 0.f);
  }
  // ---- edge 1: h2b ----
  float h2b[32];
  {
    float a[8];
#pragma unroll
    for (int i = 0; i < 8; ++i) a[i] = has1 ? ea[(size_t)e1 * 8 + i] : 0.f;
    float h1[32];
#pragma unroll
    for (int o = 0; o < 32; ++o) h1[o] = sB1[o];
#pragma unroll
    for (int i = 0; i < 8; ++i)
#pragma unroll
      for (int o = 0; o < 32; ++o) h1[o] += a[i] * sW1[i * 32 + o];
#pragma unroll
    for (int o = 0; o < 32; ++o) h1[o] = fmaxf(h1[o], 0.f);
#pragma unroll
    for (int o = 0; o < 32; ++o) h2b[o] = sB2[o];
#pragma unroll
    for (int k = 0; k < 32; ++k)
#pragma unroll
      for (int o = 0; o < 32; ++o) h2b[o] += h1[k] * sW2[k * 32 + o];
#pragma unroll
    for (int o = 0; o < 32; ++o) h2b[o] = fmaxf(h2b[o], 0.f);
  }

  float* ag0 = agg + (size_t)dst0 * 32;
  float* ag1 = agg + (size_t)dst1 * 32;
  for (int o = 0; o < 32; ++o) {  // runtime loop; reg arrays statically indexed
    float m0 = 0.f, m1 = 0.f;
#pragma unroll
    for (int i = 0; i < 8; ++i) {
      const float* wr = &sW3T[(i * 32 + o) * 32];
      float b = sB3[i * 32 + o];
      float acc0 = b, acc1 = b;
#pragma unroll
      for (int k = 0; k < 32; ++k) {
        float wv = wr[k];  // wave-uniform broadcast, shared by both edges
        acc0 += h2a[k] * wv;
        acc1 += h2b[k] * wv;
      }
      m0 += xsa[i] * fmaxf(acc0, 0.f);
      m1 += xsb[i] * fmaxf(acc1, 0.f);
    }
    atomicAdd(&ag0[o], m0);
    if (has1) atomicAdd(&ag1[o], m1);
  }
}

// out = relu(agg) -> relu(@Wl1+b) -> relu(@Wl2+b) -> @Wl3+b   (in-place on d_out)
__global__ __launch_bounds__(256) void mlp_kernel(
    const float* __restrict__ Wl1, const float* __restrict__ bl1,
    const float* __restrict__ Wl2, const float* __restrict__ bl2,
    const float* __restrict__ Wl3, const float* __restrict__ bl3,
    float* __restrict__ outp, int n) {
  __shared__ float sW[3][1024];
  __shared__ float sB[3][32];
  __shared__ float hbuf[256];
  for (int i = threadIdx.x; i < 1024; i += 256) {
    sW[0][i] = Wl1[i]; sW[1][i] = Wl2[i]; sW[2][i] = Wl3[i];
  }
  if (threadIdx.x < 32) {
    sB[0][threadIdx.x] = bl1[threadIdx.x];
    sB[1][threadIdx.x] = bl2[threadIdx.x];
    sB[2][threadIdx.x] = bl3[threadIdx.x];
  }
  __syncthreads();
  int gid = blockIdx.x * blockDim.x + threadIdx.x;
  int node = gid >> 5, o = gid & 31;
  bool active = node < n;
  float v = 0.f;
  if (active) v = fmaxf(outp[(size_t)node * 32 + o], 0.f);
  int base = threadIdx.x & ~31;
#pragma unroll
  for (int L = 0; L < 3; ++L) {
    __syncthreads();
    hbuf[threadIdx.x] = v;
    __syncthreads();
    float acc = sB[L][o];
#pragma unroll
    for (int k = 0; k < 32; ++k) acc += hbuf[base + k] * sW[L][k * 32 + o];
    v = (L < 2) ? fmaxf(acc, 0.f) : acc;
  }
  if (active) outp[(size_t)node * 32 + o] = v;
}

extern "C" void kernel_launch(void* const* d_in, const int* in_sizes, int n_in,
                              void* d_out, int out_size, void* d_ws, size_t ws_size,
                              hipStream_t stream) {
  const float* x  = (const float*)d_in[0];
  const int*   ei = (const int*)d_in[1];
  const float* ea = (const float*)d_in[2];
  const float* W1 = (const float*)d_in[3];  const float* b1  = (const float*)d_in[4];
  const float* W2 = (const float*)d_in[5];  const float* b2  = (const float*)d_in[6];
  const float* W3 = (const float*)d_in[7];  const float* b3  = (const float*)d_in[8];
  const float* Wroot = (const float*)d_in[9]; const float* ncb = (const float*)d_in[10];
  const float* Wl1 = (const float*)d_in[11]; const float* bl1 = (const float*)d_in[12];
  const float* Wl2 = (const float*)d_in[13]; const float* bl2 = (const float*)d_in[14];
  const float* Wl3 = (const float*)d_in[15]; const float* bl3 = (const float*)d_in[16];

  int n = in_sizes[0] / IN_DIM;
  int two_e = in_sizes[1];
  int nE = two_e / 2;

  float* ws = (float*)d_ws;
  float* outp = (float*)d_out;  // doubles as agg accumulator

  hipLaunchKernelGGL(init_kernel, dim3(1), dim3(256), 0, stream, ws, ei, two_e);
  hipLaunchKernelGGL(stats_kernel, dim3(256), dim3(256), 0, stream, x, n, ws);
  hipLaunchKernelGGL(finalize_stats, dim3(1), dim3(64), 0, stream, ws, 1.0f / (float)n);
  int node_blocks = (n * 32 + 255) / 256;
  hipLaunchKernelGGL(prep_kernel, dim3(node_blocks), dim3(256), 0, stream,
                     x, Wroot, ncb, ws, outp, n);
  int edge_threads = (nE + 1) / 2;
  int edge_blocks = (edge_threads + 255) / 256;
  hipLaunchKernelGGL(edge_kernel, dim3(edge_blocks), dim3(256), 0, stream,
                     ea, x, W1, b1, W2, b2, W3, b3, ws, ei, outp, nE);
  hipLaunchKernelGGL(mlp_kernel, dim3(node_blocks), dim3(256), 0, stream,
                     Wl1, bl1, Wl2, bl2, Wl3, bl3, outp, n);
}